// Round 1
// baseline (62109.570 us; speedup 1.0000x reference)
//
#include <hip/hip_runtime.h>
#include <hip/hip_bf16.h>

#define F 128
#define PROP_ITER 4

__device__ __forceinline__ float softsign(float v) { return v / (1.0f + fabsf(v)); }
__device__ __forceinline__ float sigmoidf(float v) { return 1.0f / (1.0f + expf(-v)); }

// ----------------------------------------------------------------------------
// CSR build: drop masked edges (feat > t); every node keeps its self-loop.
// ----------------------------------------------------------------------------
__global__ __launch_bounds__(256) void count_edges(const int* __restrict__ ei,
                                                   const float* __restrict__ ea,
                                                   const float* __restrict__ t,
                                                   int* __restrict__ deg, int E, int N) {
    int i = blockIdx.x * 256 + threadIdx.x;
    int tot = 2 * E + N;
    if (i >= tot) return;
    int dst; float f;
    if (i < E)            { dst = ei[E + i];   f = ea[i]; }
    else if (i < 2 * E)   { dst = ei[i - E];   f = ea[i - E]; }
    else                  { dst = i - 2 * E;   f = 1.0f; }
    if (f <= t[0]) atomicAdd(&deg[dst], 1);
}

__global__ __launch_bounds__(256) void scan_deg(const int* __restrict__ deg,
                                                int* __restrict__ row_ptr, int N) {
    __shared__ int ssum[256];
    int tid = threadIdx.x;
    int chunk = (N + 255) >> 8;
    int start = tid * chunk;
    int end = start + chunk; if (end > N) end = N; if (start > N) start = N;
    int s = 0;
    for (int i = start; i < end; i++) s += deg[i];
    ssum[tid] = s;
    __syncthreads();
    for (int off = 1; off < 256; off <<= 1) {
        int u = (tid >= off) ? ssum[tid - off] : 0;
        __syncthreads();
        ssum[tid] += u;
        __syncthreads();
    }
    int run = ssum[tid] - s;   // exclusive prefix
    for (int i = start; i < end; i++) { row_ptr[i] = run; run += deg[i]; }
    if (tid == 0) row_ptr[N] = ssum[255];
}

__global__ __launch_bounds__(256) void copy_int(const int* __restrict__ a,
                                                int* __restrict__ b, int n) {
    int i = blockIdx.x * 256 + threadIdx.x;
    if (i < n) b[i] = a[i];
}

__global__ __launch_bounds__(256) void scatter_edges(const int* __restrict__ ei,
                                                     const float* __restrict__ ea,
                                                     const float* __restrict__ t,
                                                     int* __restrict__ cursor,
                                                     int* __restrict__ col, int E, int N) {
    int i = blockIdx.x * 256 + threadIdx.x;
    int tot = 2 * E + N;
    if (i >= tot) return;
    int src, dst; float f;
    if (i < E)            { src = ei[i];      dst = ei[E + i]; f = ea[i]; }
    else if (i < 2 * E)   { src = ei[i];      dst = ei[i - E]; f = ea[i - E]; }
    else                  { src = i - 2 * E;  dst = src;       f = 1.0f; }
    if (f <= t[0]) {
        int p = atomicAdd(&cursor[dst], 1);
        col[p] = src;
    }
}

// ----------------------------------------------------------------------------
// Gate MLP: glogit[n] = (ss(ss(h W1+b1) W2+b2) W3+b3).  16 nodes / 256-thr block.
// ----------------------------------------------------------------------------
__global__ __launch_bounds__(256) void gate_mlp(const float* __restrict__ h,
                                                const float* __restrict__ W1, const float* __restrict__ b1,
                                                const float* __restrict__ W2, const float* __restrict__ b2,
                                                const float* __restrict__ W3, const float* __restrict__ b3,
                                                float* __restrict__ glogit, int N) {
    __shared__ float sh[16][130];
    __shared__ float s1[16][66];
    __shared__ float s2[16][34];
    int tid = threadIdx.x;
    int nb = blockIdx.x * 16;
    for (int i = tid; i < 16 * 128; i += 256) {
        int n = i >> 7, k = i & 127;
        int node = nb + n;
        sh[n][k] = (node < N) ? h[node * F + k] : 0.0f;
    }
    __syncthreads();
    {   // layer1: 128 -> 64, 4 cols/thread
        int n = tid >> 4, j4 = tid & 15;
        float a0 = b1[j4 * 4 + 0], a1 = b1[j4 * 4 + 1], a2 = b1[j4 * 4 + 2], a3 = b1[j4 * 4 + 3];
        for (int k = 0; k < 128; k++) {
            float hv = sh[n][k];
            float4 w = *reinterpret_cast<const float4*>(&W1[k * 64 + j4 * 4]);
            a0 += hv * w.x; a1 += hv * w.y; a2 += hv * w.z; a3 += hv * w.w;
        }
        s1[n][j4 * 4 + 0] = softsign(a0);
        s1[n][j4 * 4 + 1] = softsign(a1);
        s1[n][j4 * 4 + 2] = softsign(a2);
        s1[n][j4 * 4 + 3] = softsign(a3);
    }
    __syncthreads();
    {   // layer2: 64 -> 32, 2 cols/thread
        int n = tid >> 4, jj = tid & 15;
        float a0 = b2[jj * 2 + 0], a1 = b2[jj * 2 + 1];
        for (int k = 0; k < 64; k++) {
            float v = s1[n][k];
            float2 w = *reinterpret_cast<const float2*>(&W2[k * 32 + jj * 2]);
            a0 += v * w.x; a1 += v * w.y;
        }
        s2[n][jj * 2 + 0] = softsign(a0);
        s2[n][jj * 2 + 1] = softsign(a1);
    }
    __syncthreads();
    {   // layer3: 32 -> 1, reduce over 16 lanes (masks < 16 stay in group)
        int n = tid >> 4, jj = tid & 15;
        float p = s2[n][jj] * W3[jj] + s2[n][jj + 16] * W3[jj + 16];
        p += __shfl_xor(p, 1);
        p += __shfl_xor(p, 2);
        p += __shfl_xor(p, 4);
        p += __shfl_xor(p, 8);
        if (jj == 0) {
            int node = nb + n;
            if (node < N) glogit[node] = p + b3[0];
        }
    }
}

// ----------------------------------------------------------------------------
// Softmax aggregation over incoming edges (CSR).  1 wave per dst node.
// m[dst] = sum_e w_e * h[src_e] / sum_e w_e,  w_e = exp(g[src_e] - max).
// ----------------------------------------------------------------------------
__global__ __launch_bounds__(64) void aggregate(const float* __restrict__ h,
                                                const float* __restrict__ glogit,
                                                const int* __restrict__ row_ptr,
                                                const int* __restrict__ col,
                                                float* __restrict__ m, int N) {
    int dst = blockIdx.x;
    if (dst >= N) return;
    int lane = threadIdx.x;
    int e0 = row_ptr[dst], e1 = row_ptr[dst + 1];
    float mx = -1e30f;
    for (int e = e0 + lane; e < e1; e += 64) mx = fmaxf(mx, glogit[col[e]]);
    #pragma unroll
    for (int o = 32; o; o >>= 1) mx = fmaxf(mx, __shfl_xor(mx, o));
    float acc0 = 0.0f, acc1 = 0.0f, denom = 0.0f;
    for (int e = e0; e < e1; e++) {
        int s = col[e];
        float w = expf(glogit[s] - mx);
        denom += w;
        acc0 += w * h[s * F + lane];
        acc1 += w * h[s * F + 64 + lane];
    }
    float inv = 1.0f / denom;   // self-loop guarantees denom > 0
    m[dst * F + lane] = acc0 * inv;
    m[dst * F + 64 + lane] = acc1 * inv;
}

// ----------------------------------------------------------------------------
// GRU cell, tiled: 32 nodes/block, 256 threads, 2x2 register tile.
// Weight chunks (32 outs x 128 K) staged in LDS -> each block reads full
// 393KB of GRU weights exactly once (L2-hot).
// ----------------------------------------------------------------------------
#define GMT 32

__device__ __forceinline__ void stage_mm(const float* __restrict__ W, int obase,
                                         const float (*__restrict__ SRC)[132],
                                         float (&sw)[32][132],
                                         float (&acc)[2][2], int tid, int ty, int tx) {
    __syncthreads();                 // protect previous sw consumers
    for (int i2 = tid; i2 < 1024; i2 += 256) {
        int rr = i2 >> 5, k4 = i2 & 31;
        *reinterpret_cast<float4*>(&sw[rr][k4 * 4]) =
            *reinterpret_cast<const float4*>(&W[(obase + rr) * 128 + k4 * 4]);
    }
    __syncthreads();
    float a00 = 0.f, a01 = 0.f, a10 = 0.f, a11 = 0.f;
    for (int k4 = 0; k4 < 32; k4++) {
        float4 w0 = *reinterpret_cast<const float4*>(&sw[tx][k4 * 4]);
        float4 w1 = *reinterpret_cast<const float4*>(&sw[tx + 16][k4 * 4]);
        float4 m0 = *reinterpret_cast<const float4*>(&SRC[ty][k4 * 4]);
        float4 m1 = *reinterpret_cast<const float4*>(&SRC[ty + 16][k4 * 4]);
        a00 += m0.x * w0.x + m0.y * w0.y + m0.z * w0.z + m0.w * w0.w;
        a01 += m0.x * w1.x + m0.y * w1.y + m0.z * w1.z + m0.w * w1.w;
        a10 += m1.x * w0.x + m1.y * w0.y + m1.z * w0.z + m1.w * w0.w;
        a11 += m1.x * w1.x + m1.y * w1.y + m1.z * w1.z + m1.w * w1.w;
    }
    acc[0][0] = a00; acc[0][1] = a01; acc[1][0] = a10; acc[1][1] = a11;
}

__global__ __launch_bounds__(256) void gru_kernel(const float* __restrict__ mbuf,
                                                  const float* __restrict__ h,
                                                  const float* __restrict__ Wih,
                                                  const float* __restrict__ Whh,
                                                  const float* __restrict__ bih,
                                                  const float* __restrict__ bhh,
                                                  float* __restrict__ hnew, int N) {
    __shared__ float sm[GMT][132];
    __shared__ float shh[GMT][132];
    __shared__ float sw[32][132];
    int tid = threadIdx.x;
    int ty = tid >> 4, tx = tid & 15;
    int nb = blockIdx.x * GMT;
    for (int i = tid; i < GMT * 32; i += 256) {
        int n = i >> 5, k4 = i & 31;
        int node = nb + n;
        float4 vm = make_float4(0.f, 0.f, 0.f, 0.f), vh = vm;
        if (node < N) {
            vm = *reinterpret_cast<const float4*>(&mbuf[node * F + k4 * 4]);
            vh = *reinterpret_cast<const float4*>(&h[node * F + k4 * 4]);
        }
        *reinterpret_cast<float4*>(&sm[n][k4 * 4]) = vm;
        *reinterpret_cast<float4*>(&shh[n][k4 * 4]) = vh;
    }
    float air[2][2], aiz[2][2], aig[2][2], ahr[2][2], ahz[2][2], ahg[2][2];
    for (int fc = 0; fc < 4; fc++) {
        stage_mm(Wih,   0 + fc * 32, sm,  sw, air, tid, ty, tx);
        stage_mm(Wih, 128 + fc * 32, sm,  sw, aiz, tid, ty, tx);
        stage_mm(Wih, 256 + fc * 32, sm,  sw, aig, tid, ty, tx);
        stage_mm(Whh,   0 + fc * 32, shh, sw, ahr, tid, ty, tx);
        stage_mm(Whh, 128 + fc * 32, shh, sw, ahz, tid, ty, tx);
        stage_mm(Whh, 256 + fc * 32, shh, sw, ahg, tid, ty, tx);
        #pragma unroll
        for (int i = 0; i < 2; i++) {
            int row = ty + 16 * i;
            int node = nb + row;
            #pragma unroll
            for (int jc = 0; jc < 2; jc++) {
                int f = fc * 32 + tx + 16 * jc;
                float ir = air[i][jc] + bih[f];
                float iz = aiz[i][jc] + bih[128 + f];
                float ig = aig[i][jc] + bih[256 + f];
                float hr = ahr[i][jc] + bhh[f];
                float hz = ahz[i][jc] + bhh[128 + f];
                float hg = ahg[i][jc] + bhh[256 + f];
                float r = sigmoidf(ir + hr);
                float z = sigmoidf(iz + hz);
                float cand = tanhf(ig + r * hg);
                if (node < N) hnew[node * F + f] = (1.0f - z) * cand + z * shh[row][f];
            }
        }
    }
}

// ----------------------------------------------------------------------------
// Final attention: ai1 = ss([h|x] W1 + b1).  8 nodes/block, 4 nodes/thread.
// ----------------------------------------------------------------------------
__global__ __launch_bounds__(256) void attn_l1(const float* __restrict__ h,
                                               const float* __restrict__ x,
                                               const float* __restrict__ W1,
                                               const float* __restrict__ b1,
                                               float* __restrict__ ai1, int N) {
    __shared__ float sf[8][258];
    int tid = threadIdx.x;
    int node0 = blockIdx.x * 8;
    for (int i = tid; i < 8 * 256; i += 256) {
        int n = i >> 8, k = i & 255;
        int nd = node0 + n;
        float v = 0.f;
        if (nd < N) v = (k < 128) ? h[nd * F + k] : x[nd * F + (k - 128)];
        sf[n][k] = v;
    }
    __syncthreads();
    int n2 = tid >> 7, j = tid & 127;
    float a[4];
    #pragma unroll
    for (int i = 0; i < 4; i++) a[i] = b1[j];
    for (int k = 0; k < 256; k++) {
        float w = W1[k * 128 + j];
        a[0] += sf[n2 + 0][k] * w;
        a[1] += sf[n2 + 2][k] * w;
        a[2] += sf[n2 + 4][k] * w;
        a[3] += sf[n2 + 6][k] * w;
    }
    #pragma unroll
    for (int i = 0; i < 4; i++) {
        int nd = node0 + n2 + 2 * i;
        if (nd < N) ai1[nd * F + j] = softsign(a[i]);
    }
}

// ----------------------------------------------------------------------------
// ai2 = ss(ai1 W2 + b2); attn = softmax_row(ai2); aj = ss(x Wj + bj);
// node_out = attn * aj.   8 nodes/block.
// ----------------------------------------------------------------------------
__global__ __launch_bounds__(256) void attn_l2(const float* __restrict__ ai1,
                                               const float* __restrict__ x,
                                               const float* __restrict__ W2,
                                               const float* __restrict__ b2,
                                               const float* __restrict__ Wj,
                                               const float* __restrict__ bj,
                                               float* __restrict__ node_out, int N) {
    __shared__ float sa[8][130];
    __shared__ float sx[8][130];
    __shared__ float sred[8][128];
    int tid = threadIdx.x;
    int node0 = blockIdx.x * 8;
    for (int i = tid; i < 8 * 128; i += 256) {
        int n = i >> 7, k = i & 127;
        int nd = node0 + n;
        sa[n][k] = (nd < N) ? ai1[nd * F + k] : 0.f;
        sx[n][k] = (nd < N) ? x[nd * F + k] : 0.f;
    }
    __syncthreads();
    int n2 = tid >> 7, j = tid & 127;
    float acc[4], accj[4];
    #pragma unroll
    for (int i = 0; i < 4; i++) { acc[i] = b2[j]; accj[i] = bj[j]; }
    for (int k = 0; k < 128; k++) {
        float w2 = W2[k * 128 + j];
        float wj = Wj[k * 128 + j];
        #pragma unroll
        for (int i = 0; i < 4; i++) {
            acc[i]  += sa[n2 + 2 * i][k] * w2;
            accj[i] += sx[n2 + 2 * i][k] * wj;
        }
    }
    float v[4], aj[4];
    #pragma unroll
    for (int i = 0; i < 4; i++) {
        v[i] = softsign(acc[i]);
        aj[i] = softsign(accj[i]);
        sred[n2 + 2 * i][j] = v[i];
    }
    __syncthreads();
    for (int s = 64; s > 0; s >>= 1) {
        if (j < s) {
            #pragma unroll
            for (int i = 0; i < 4; i++) {
                int r = n2 + 2 * i;
                sred[r][j] = fmaxf(sred[r][j], sred[r][j + s]);
            }
        }
        __syncthreads();
    }
    float mx[4];
    #pragma unroll
    for (int i = 0; i < 4; i++) mx[i] = sred[n2 + 2 * i][0];
    __syncthreads();
    float e[4];
    #pragma unroll
    for (int i = 0; i < 4; i++) {
        e[i] = expf(v[i] - mx[i]);
        sred[n2 + 2 * i][j] = e[i];
    }
    __syncthreads();
    for (int s = 64; s > 0; s >>= 1) {
        if (j < s) {
            #pragma unroll
            for (int i = 0; i < 4; i++) {
                int r = n2 + 2 * i;
                sred[r][j] += sred[r][j + s];
            }
        }
        __syncthreads();
    }
    #pragma unroll
    for (int i = 0; i < 4; i++) {
        float sum = sred[n2 + 2 * i][0];
        int nd = node0 + n2 + 2 * i;
        if (nd < N) node_out[nd * F + j] = (e[i] / sum) * aj[i];
    }
}

// ----------------------------------------------------------------------------
// Graph pooling (batch = node / (N/G), contiguous) + out MLP.
// ----------------------------------------------------------------------------
__global__ __launch_bounds__(128) void pool_kernel(const float* __restrict__ node_out,
                                                   float* __restrict__ pooled,
                                                   int npg, int N) {
    int g = blockIdx.x, part = blockIdx.y, j = threadIdx.x;
    int start = g * npg + (part * npg) / 8;
    int end   = g * npg + ((part + 1) * npg) / 8;
    if (end > N) end = N;
    float s = 0.f;
    for (int nd = start; nd < end; nd++) s += node_out[nd * F + j];
    atomicAdd(&pooled[g * F + j], s);
}

__global__ __launch_bounds__(128) void out_mlp(const float* __restrict__ pooled,
                                               const float* __restrict__ W1, const float* __restrict__ b1,
                                               const float* __restrict__ W2, const float* __restrict__ b2,
                                               const float* __restrict__ W3, const float* __restrict__ b3,
                                               float* __restrict__ out, int H1, int H2) {
    __shared__ float sp[128];
    __shared__ float s1[96];
    __shared__ float s2[64];
    int g = blockIdx.x, j = threadIdx.x;
    sp[j] = pooled[g * F + j];
    __syncthreads();
    if (j < H1) {
        float a = b1[j];
        for (int k = 0; k < 128; k++) a += sp[k] * W1[k * H1 + j];
        s1[j] = fmaxf(a, 0.f);
    }
    __syncthreads();
    if (j < H2) {
        float a = b2[j];
        for (int k = 0; k < H1; k++) a += s1[k] * W2[k * H2 + j];
        s2[j] = fmaxf(a, 0.f);
    }
    __syncthreads();
    if (j == 0) {
        float a = b3[0];
        for (int k = 0; k < H2; k++) a += s2[k] * W3[k];
        out[g] = a;
    }
}

// ----------------------------------------------------------------------------
extern "C" void kernel_launch(void* const* d_in, const int* in_sizes, int n_in,
                              void* d_out, int out_size, void* d_ws, size_t ws_size,
                              hipStream_t stream) {
    const float* x    = (const float*)d_in[0];
    const int*   ei   = (const int*)  d_in[1];
    const float* ea   = (const float*)d_in[2];
    const float* t    = (const float*)d_in[4];
    const float* gW1  = (const float*)d_in[5];
    const float* gb1  = (const float*)d_in[6];
    const float* gW2  = (const float*)d_in[7];
    const float* gb2  = (const float*)d_in[8];
    const float* gW3  = (const float*)d_in[9];
    const float* gb3  = (const float*)d_in[10];
    const float* Wih  = (const float*)d_in[11];
    const float* Whh  = (const float*)d_in[12];
    const float* bih  = (const float*)d_in[13];
    const float* bhh  = (const float*)d_in[14];
    const float* aiW1 = (const float*)d_in[15];
    const float* aib1 = (const float*)d_in[16];
    const float* aiW2 = (const float*)d_in[17];
    const float* aib2 = (const float*)d_in[18];
    const float* ajW  = (const float*)d_in[19];
    const float* ajb  = (const float*)d_in[20];
    const float* oW1  = (const float*)d_in[21];
    const float* ob1  = (const float*)d_in[22];
    const float* oW2  = (const float*)d_in[23];
    const float* ob2  = (const float*)d_in[24];
    const float* oW3  = (const float*)d_in[25];
    const float* ob3  = (const float*)d_in[26];
    float* out = (float*)d_out;

    const int N = in_sizes[0] / F;
    const int E = in_sizes[2];
    const int G = out_size;         // OUT == 1
    const int npg = N / G;
    const int H1 = 85, H2 = 64;     // int(128/1.5), 128//2
    const int Etot = 2 * E + N;

    // workspace carve-up (256B aligned)
    char* w = (char*)d_ws;
    auto carve = [&](size_t bytes) {
        void* p = (void*)w;
        w += (bytes + 255) & ~(size_t)255;
        return p;
    };
    int*   deg     = (int*)  carve((size_t)N * 4);
    int*   row_ptr = (int*)  carve((size_t)(N + 1) * 4);
    int*   cursor  = (int*)  carve((size_t)N * 4);
    int*   col     = (int*)  carve((size_t)Etot * 4);
    float* glogit  = (float*)carve((size_t)N * 4);
    float* hA      = (float*)carve((size_t)N * F * 4);
    float* hB      = (float*)carve((size_t)N * F * 4);
    float* mbuf    = (float*)carve((size_t)N * F * 4);
    float* pooled  = (float*)carve((size_t)G * F * 4);
    (void)ws_size; (void)n_in;

    // --- CSR build ---
    hipMemsetAsync(deg, 0, (size_t)N * 4, stream);
    int eb = (Etot + 255) / 256;
    count_edges<<<eb, 256, 0, stream>>>(ei, ea, t, deg, E, N);
    scan_deg<<<1, 256, 0, stream>>>(deg, row_ptr, N);
    copy_int<<<(N + 255) / 256, 256, 0, stream>>>(row_ptr, cursor, N);
    scatter_edges<<<eb, 256, 0, stream>>>(ei, ea, t, cursor, col, E, N);

    // --- h = x ---
    hipMemcpyAsync(hA, x, (size_t)N * F * 4, hipMemcpyDeviceToDevice, stream);

    float* hc = hA;
    float* hn = hB;
    for (int it = 0; it < PROP_ITER; it++) {
        gate_mlp<<<(N + 15) / 16, 256, 0, stream>>>(hc, gW1, gb1, gW2, gb2, gW3, gb3, glogit, N);
        aggregate<<<N, 64, 0, stream>>>(hc, glogit, row_ptr, col, mbuf, N);
        gru_kernel<<<(N + GMT - 1) / GMT, 256, 0, stream>>>(mbuf, hc, Wih, Whh, bih, bhh, hn, N);
        float* tmp = hc; hc = hn; hn = tmp;
    }

    // --- final attention (ai1 reuses mbuf, node_out reuses the free h buffer) ---
    attn_l1<<<(N + 7) / 8, 256, 0, stream>>>(hc, x, aiW1, aib1, mbuf, N);
    attn_l2<<<(N + 7) / 8, 256, 0, stream>>>(mbuf, x, aiW2, aib2, ajW, ajb, hn, N);

    hipMemsetAsync(pooled, 0, (size_t)G * F * 4, stream);
    dim3 pg(G, 8);
    pool_kernel<<<pg, 128, 0, stream>>>(hn, pooled, npg, N);
    out_mlp<<<G, 128, 0, stream>>>(pooled, oW1, ob1, oW2, ob2, oW3, ob3, out, H1, H2);
}

// Round 2
// 2141.707 us; speedup vs baseline: 29.0000x; 29.0000x over previous
//
#include <hip/hip_runtime.h>
#include <hip/hip_bf16.h>

#define F 128
#define PROP_ITER 4

__device__ __forceinline__ float softsign(float v) { return v / (1.0f + fabsf(v)); }
__device__ __forceinline__ float sigmoidf(float v) { return 1.0f / (1.0f + expf(-v)); }

// ----------------------------------------------------------------------------
// CSR build: drop masked edges (feat > t); every node keeps its self-loop.
// ----------------------------------------------------------------------------
__global__ __launch_bounds__(256) void count_edges(const int* __restrict__ ei,
                                                   const float* __restrict__ ea,
                                                   const float* __restrict__ t,
                                                   int* __restrict__ deg, int E, int N) {
    int i = blockIdx.x * 256 + threadIdx.x;
    int tot = 2 * E + N;
    if (i >= tot) return;
    int dst; float f;
    if (i < E)            { dst = ei[E + i];   f = ea[i]; }
    else if (i < 2 * E)   { dst = ei[i - E];   f = ea[i - E]; }
    else                  { dst = i - 2 * E;   f = 1.0f; }
    if (f <= t[0]) atomicAdd(&deg[dst], 1);
}

__global__ __launch_bounds__(256) void scan_deg(const int* __restrict__ deg,
                                                int* __restrict__ row_ptr, int N) {
    __shared__ int ssum[256];
    int tid = threadIdx.x;
    int chunk = (N + 255) >> 8;
    int start = tid * chunk;
    int end = start + chunk; if (end > N) end = N; if (start > N) start = N;
    int s = 0;
    for (int i = start; i < end; i++) s += deg[i];
    ssum[tid] = s;
    __syncthreads();
    for (int off = 1; off < 256; off <<= 1) {
        int u = (tid >= off) ? ssum[tid - off] : 0;
        __syncthreads();
        ssum[tid] += u;
        __syncthreads();
    }
    int run = ssum[tid] - s;   // exclusive prefix
    for (int i = start; i < end; i++) { row_ptr[i] = run; run += deg[i]; }
    if (tid == 0) row_ptr[N] = ssum[255];
}

__global__ __launch_bounds__(256) void copy_int(const int* __restrict__ a,
                                                int* __restrict__ b, int n) {
    int i = blockIdx.x * 256 + threadIdx.x;
    if (i < n) b[i] = a[i];
}

__global__ __launch_bounds__(256) void scatter_edges(const int* __restrict__ ei,
                                                     const float* __restrict__ ea,
                                                     const float* __restrict__ t,
                                                     int* __restrict__ cursor,
                                                     int* __restrict__ col, int E, int N) {
    int i = blockIdx.x * 256 + threadIdx.x;
    int tot = 2 * E + N;
    if (i >= tot) return;
    int src, dst; float f;
    if (i < E)            { src = ei[i];      dst = ei[E + i]; f = ea[i]; }
    else if (i < 2 * E)   { src = ei[i];      dst = ei[i - E]; f = ea[i - E]; }
    else                  { src = i - 2 * E;  dst = src;       f = 1.0f; }
    if (f <= t[0]) {
        int p = atomicAdd(&cursor[dst], 1);
        col[p] = src;
    }
}

// ----------------------------------------------------------------------------
// Gate MLP: glogit[n] = (ss(ss(h W1+b1) W2+b2) W3+b3).  16 nodes / 256-thr block.
// ----------------------------------------------------------------------------
__global__ __launch_bounds__(256) void gate_mlp(const float* __restrict__ h,
                                                const float* __restrict__ W1, const float* __restrict__ b1,
                                                const float* __restrict__ W2, const float* __restrict__ b2,
                                                const float* __restrict__ W3, const float* __restrict__ b3,
                                                float* __restrict__ glogit, int N) {
    __shared__ float sh[16][130];
    __shared__ float s1[16][66];
    __shared__ float s2[16][34];
    int tid = threadIdx.x;
    int nb = blockIdx.x * 16;
    for (int i = tid; i < 16 * 128; i += 256) {
        int n = i >> 7, k = i & 127;
        int node = nb + n;
        sh[n][k] = (node < N) ? h[node * F + k] : 0.0f;
    }
    __syncthreads();
    {   // layer1: 128 -> 64, 4 cols/thread
        int n = tid >> 4, j4 = tid & 15;
        float a0 = b1[j4 * 4 + 0], a1 = b1[j4 * 4 + 1], a2 = b1[j4 * 4 + 2], a3 = b1[j4 * 4 + 3];
        for (int k = 0; k < 128; k++) {
            float hv = sh[n][k];
            float4 w = *reinterpret_cast<const float4*>(&W1[k * 64 + j4 * 4]);
            a0 += hv * w.x; a1 += hv * w.y; a2 += hv * w.z; a3 += hv * w.w;
        }
        s1[n][j4 * 4 + 0] = softsign(a0);
        s1[n][j4 * 4 + 1] = softsign(a1);
        s1[n][j4 * 4 + 2] = softsign(a2);
        s1[n][j4 * 4 + 3] = softsign(a3);
    }
    __syncthreads();
    {   // layer2: 64 -> 32, 2 cols/thread
        int n = tid >> 4, jj = tid & 15;
        float a0 = b2[jj * 2 + 0], a1 = b2[jj * 2 + 1];
        for (int k = 0; k < 64; k++) {
            float v = s1[n][k];
            float2 w = *reinterpret_cast<const float2*>(&W2[k * 32 + jj * 2]);
            a0 += v * w.x; a1 += v * w.y;
        }
        s2[n][jj * 2 + 0] = softsign(a0);
        s2[n][jj * 2 + 1] = softsign(a1);
    }
    __syncthreads();
    {   // layer3: 32 -> 1, reduce over 16 lanes (masks < 16 stay in group)
        int n = tid >> 4, jj = tid & 15;
        float p = s2[n][jj] * W3[jj] + s2[n][jj + 16] * W3[jj + 16];
        p += __shfl_xor(p, 1);
        p += __shfl_xor(p, 2);
        p += __shfl_xor(p, 4);
        p += __shfl_xor(p, 8);
        if (jj == 0) {
            int node = nb + n;
            if (node < N) glogit[node] = p + b3[0];
        }
    }
}

// ----------------------------------------------------------------------------
// Softmax aggregation over incoming edges (CSR).  1 wave per dst node.
// ----------------------------------------------------------------------------
__global__ __launch_bounds__(64) void aggregate(const float* __restrict__ h,
                                                const float* __restrict__ glogit,
                                                const int* __restrict__ row_ptr,
                                                const int* __restrict__ col,
                                                float* __restrict__ m, int N) {
    int dst = blockIdx.x;
    if (dst >= N) return;
    int lane = threadIdx.x;
    int e0 = row_ptr[dst], e1 = row_ptr[dst + 1];
    float mx = -1e30f;
    for (int e = e0 + lane; e < e1; e += 64) mx = fmaxf(mx, glogit[col[e]]);
    #pragma unroll
    for (int o = 32; o; o >>= 1) mx = fmaxf(mx, __shfl_xor(mx, o));
    float acc0 = 0.0f, acc1 = 0.0f, denom = 0.0f;
    for (int e = e0; e < e1; e++) {
        int s = col[e];
        float w = expf(glogit[s] - mx);
        denom += w;
        acc0 += w * h[s * F + lane];
        acc1 += w * h[s * F + 64 + lane];
    }
    float inv = 1.0f / denom;   // self-loop guarantees denom > 0
    m[dst * F + lane] = acc0 * inv;
    m[dst * F + 64 + lane] = acc1 * inv;
}

// ----------------------------------------------------------------------------
// GRU cell, restructured to avoid register spill:
//   - 32 nodes/block, 256 threads.
//   - For each 32-feature chunk: run the SIX 32x32 chunk-GEMMs sequentially
//     (one 2x2 accumulator quad live at a time), dumping results to LDS
//     sg[6][32][33], then a fused epilogue writes hnew for that chunk.
//   - #pragma unroll 1 on the chunk loops keeps codegen small (no 24-body
//     unroll that caused the round-1 256-VGPR spill).
// ----------------------------------------------------------------------------
__global__ __launch_bounds__(256) void gru_kernel(const float* __restrict__ mbuf,
                                                  const float* __restrict__ h,
                                                  const float* __restrict__ Wih,
                                                  const float* __restrict__ Whh,
                                                  const float* __restrict__ bih,
                                                  const float* __restrict__ bhh,
                                                  float* __restrict__ hnew, int N) {
    __shared__ float sm[32][132];
    __shared__ float sh[32][132];
    __shared__ float sw[32][132];
    __shared__ float sg[6][32][33];
    int tid = threadIdx.x;
    int ty = tid >> 4, tx = tid & 15;
    int nb = blockIdx.x * 32;

    for (int i = tid; i < 32 * 32; i += 256) {
        int n = i >> 5, k4 = i & 31;
        int node = nb + n;
        float4 vm = make_float4(0.f, 0.f, 0.f, 0.f), vh = vm;
        if (node < N) {
            vm = *reinterpret_cast<const float4*>(&mbuf[node * F + k4 * 4]);
            vh = *reinterpret_cast<const float4*>(&h[node * F + k4 * 4]);
        }
        *reinterpret_cast<float4*>(&sm[n][k4 * 4]) = vm;
        *reinterpret_cast<float4*>(&sh[n][k4 * 4]) = vh;
    }

    #pragma unroll 1
    for (int fc = 0; fc < 4; fc++) {
        #pragma unroll 1
        for (int c = 0; c < 6; c++) {
            const float* W = (c < 3) ? Wih : Whh;
            int obase = (c % 3) * 128 + fc * 32;
            __syncthreads();   // previous consumers of sw / sg epilogue done
            for (int i2 = tid; i2 < 1024; i2 += 256) {
                int rr = i2 >> 5, k4 = i2 & 31;
                *reinterpret_cast<float4*>(&sw[rr][k4 * 4]) =
                    *reinterpret_cast<const float4*>(&W[(obase + rr) * F + k4 * 4]);
            }
            __syncthreads();
            const float (*SRC)[132] = (c < 3) ? sm : sh;
            float a00 = 0.f, a01 = 0.f, a10 = 0.f, a11 = 0.f;
            #pragma unroll 4
            for (int k4 = 0; k4 < 32; k4++) {
                float4 w0 = *reinterpret_cast<const float4*>(&sw[tx][k4 * 4]);
                float4 w1 = *reinterpret_cast<const float4*>(&sw[tx + 16][k4 * 4]);
                float4 m0 = *reinterpret_cast<const float4*>(&SRC[ty][k4 * 4]);
                float4 m1 = *reinterpret_cast<const float4*>(&SRC[ty + 16][k4 * 4]);
                a00 += m0.x * w0.x + m0.y * w0.y + m0.z * w0.z + m0.w * w0.w;
                a01 += m0.x * w1.x + m0.y * w1.y + m0.z * w1.z + m0.w * w1.w;
                a10 += m1.x * w0.x + m1.y * w0.y + m1.z * w0.z + m1.w * w0.w;
                a11 += m1.x * w1.x + m1.y * w1.y + m1.z * w1.z + m1.w * w1.w;
            }
            sg[c][ty][tx]           = a00;
            sg[c][ty][tx + 16]      = a01;
            sg[c][ty + 16][tx]      = a10;
            sg[c][ty + 16][tx + 16] = a11;
        }
        __syncthreads();
        // epilogue for this 32-feature chunk
        for (int i2 = tid; i2 < 1024; i2 += 256) {
            int n = i2 >> 5, ff = i2 & 31;
            int f = fc * 32 + ff;
            int node = nb + n;
            float ir = sg[0][n][ff] + bih[f];
            float iz = sg[1][n][ff] + bih[128 + f];
            float ig = sg[2][n][ff] + bih[256 + f];
            float hr = sg[3][n][ff] + bhh[f];
            float hz = sg[4][n][ff] + bhh[128 + f];
            float hg = sg[5][n][ff] + bhh[256 + f];
            float r = sigmoidf(ir + hr);
            float z = sigmoidf(iz + hz);
            float cand = tanhf(ig + r * hg);
            if (node < N) hnew[node * F + f] = (1.0f - z) * cand + z * sh[n][f];
        }
    }
}

// ----------------------------------------------------------------------------
// Final attention: ai1 = ss([h|x] W1 + b1).  8 nodes/block, 4 nodes/thread.
// ----------------------------------------------------------------------------
__global__ __launch_bounds__(256) void attn_l1(const float* __restrict__ h,
                                               const float* __restrict__ x,
                                               const float* __restrict__ W1,
                                               const float* __restrict__ b1,
                                               float* __restrict__ ai1, int N) {
    __shared__ float sf[8][258];
    int tid = threadIdx.x;
    int node0 = blockIdx.x * 8;
    for (int i = tid; i < 8 * 256; i += 256) {
        int n = i >> 8, k = i & 255;
        int nd = node0 + n;
        float v = 0.f;
        if (nd < N) v = (k < 128) ? h[nd * F + k] : x[nd * F + (k - 128)];
        sf[n][k] = v;
    }
    __syncthreads();
    int n2 = tid >> 7, j = tid & 127;
    float a[4];
    #pragma unroll
    for (int i = 0; i < 4; i++) a[i] = b1[j];
    for (int k = 0; k < 256; k++) {
        float w = W1[k * 128 + j];
        a[0] += sf[n2 + 0][k] * w;
        a[1] += sf[n2 + 2][k] * w;
        a[2] += sf[n2 + 4][k] * w;
        a[3] += sf[n2 + 6][k] * w;
    }
    #pragma unroll
    for (int i = 0; i < 4; i++) {
        int nd = node0 + n2 + 2 * i;
        if (nd < N) ai1[nd * F + j] = softsign(a[i]);
    }
}

// ----------------------------------------------------------------------------
// ai2 = ss(ai1 W2 + b2); attn = softmax_row(ai2); aj = ss(x Wj + bj);
// node_out = attn * aj.   8 nodes/block.
// ----------------------------------------------------------------------------
__global__ __launch_bounds__(256) void attn_l2(const float* __restrict__ ai1,
                                               const float* __restrict__ x,
                                               const float* __restrict__ W2,
                                               const float* __restrict__ b2,
                                               const float* __restrict__ Wj,
                                               const float* __restrict__ bj,
                                               float* __restrict__ node_out, int N) {
    __shared__ float sa[8][130];
    __shared__ float sx[8][130];
    __shared__ float sred[8][128];
    int tid = threadIdx.x;
    int node0 = blockIdx.x * 8;
    for (int i = tid; i < 8 * 128; i += 256) {
        int n = i >> 7, k = i & 127;
        int nd = node0 + n;
        sa[n][k] = (nd < N) ? ai1[nd * F + k] : 0.f;
        sx[n][k] = (nd < N) ? x[nd * F + k] : 0.f;
    }
    __syncthreads();
    int n2 = tid >> 7, j = tid & 127;
    float acc[4], accj[4];
    #pragma unroll
    for (int i = 0; i < 4; i++) { acc[i] = b2[j]; accj[i] = bj[j]; }
    for (int k = 0; k < 128; k++) {
        float w2 = W2[k * 128 + j];
        float wj = Wj[k * 128 + j];
        #pragma unroll
        for (int i = 0; i < 4; i++) {
            acc[i]  += sa[n2 + 2 * i][k] * w2;
            accj[i] += sx[n2 + 2 * i][k] * wj;
        }
    }
    float v[4], aj[4];
    #pragma unroll
    for (int i = 0; i < 4; i++) {
        v[i] = softsign(acc[i]);
        aj[i] = softsign(accj[i]);
        sred[n2 + 2 * i][j] = v[i];
    }
    __syncthreads();
    for (int s = 64; s > 0; s >>= 1) {
        if (j < s) {
            #pragma unroll
            for (int i = 0; i < 4; i++) {
                int r = n2 + 2 * i;
                sred[r][j] = fmaxf(sred[r][j], sred[r][j + s]);
            }
        }
        __syncthreads();
    }
    float mx[4];
    #pragma unroll
    for (int i = 0; i < 4; i++) mx[i] = sred[n2 + 2 * i][0];
    __syncthreads();
    float e[4];
    #pragma unroll
    for (int i = 0; i < 4; i++) {
        e[i] = expf(v[i] - mx[i]);
        sred[n2 + 2 * i][j] = e[i];
    }
    __syncthreads();
    for (int s = 64; s > 0; s >>= 1) {
        if (j < s) {
            #pragma unroll
            for (int i = 0; i < 4; i++) {
                int r = n2 + 2 * i;
                sred[r][j] += sred[r][j + s];
            }
        }
        __syncthreads();
    }
    #pragma unroll
    for (int i = 0; i < 4; i++) {
        float sum = sred[n2 + 2 * i][0];
        int nd = node0 + n2 + 2 * i;
        if (nd < N) node_out[nd * F + j] = (e[i] / sum) * aj[i];
    }
}

// ----------------------------------------------------------------------------
// Graph pooling (batch = node / (N/G), contiguous) + out MLP.
// ----------------------------------------------------------------------------
__global__ __launch_bounds__(128) void pool_kernel(const float* __restrict__ node_out,
                                                   float* __restrict__ pooled,
                                                   int npg, int N) {
    int g = blockIdx.x, part = blockIdx.y, j = threadIdx.x;
    int start = g * npg + (part * npg) / 8;
    int end   = g * npg + ((part + 1) * npg) / 8;
    if (end > N) end = N;
    float s = 0.f;
    for (int nd = start; nd < end; nd++) s += node_out[nd * F + j];
    atomicAdd(&pooled[g * F + j], s);
}

__global__ __launch_bounds__(128) void out_mlp(const float* __restrict__ pooled,
                                               const float* __restrict__ W1, const float* __restrict__ b1,
                                               const float* __restrict__ W2, const float* __restrict__ b2,
                                               const float* __restrict__ W3, const float* __restrict__ b3,
                                               float* __restrict__ out, int H1, int H2) {
    __shared__ float sp[128];
    __shared__ float s1[96];
    __shared__ float s2[64];
    int g = blockIdx.x, j = threadIdx.x;
    sp[j] = pooled[g * F + j];
    __syncthreads();
    if (j < H1) {
        float a = b1[j];
        for (int k = 0; k < 128; k++) a += sp[k] * W1[k * H1 + j];
        s1[j] = fmaxf(a, 0.f);
    }
    __syncthreads();
    if (j < H2) {
        float a = b2[j];
        for (int k = 0; k < H1; k++) a += s1[k] * W2[k * H2 + j];
        s2[j] = fmaxf(a, 0.f);
    }
    __syncthreads();
    if (j == 0) {
        float a = b3[0];
        for (int k = 0; k < H2; k++) a += s2[k] * W3[k];
        out[g] = a;
    }
}

// ----------------------------------------------------------------------------
extern "C" void kernel_launch(void* const* d_in, const int* in_sizes, int n_in,
                              void* d_out, int out_size, void* d_ws, size_t ws_size,
                              hipStream_t stream) {
    const float* x    = (const float*)d_in[0];
    const int*   ei   = (const int*)  d_in[1];
    const float* ea   = (const float*)d_in[2];
    const float* t    = (const float*)d_in[4];
    const float* gW1  = (const float*)d_in[5];
    const float* gb1  = (const float*)d_in[6];
    const float* gW2  = (const float*)d_in[7];
    const float* gb2  = (const float*)d_in[8];
    const float* gW3  = (const float*)d_in[9];
    const float* gb3  = (const float*)d_in[10];
    const float* Wih  = (const float*)d_in[11];
    const float* Whh  = (const float*)d_in[12];
    const float* bih  = (const float*)d_in[13];
    const float* bhh  = (const float*)d_in[14];
    const float* aiW1 = (const float*)d_in[15];
    const float* aib1 = (const float*)d_in[16];
    const float* aiW2 = (const float*)d_in[17];
    const float* aib2 = (const float*)d_in[18];
    const float* ajW  = (const float*)d_in[19];
    const float* ajb  = (const float*)d_in[20];
    const float* oW1  = (const float*)d_in[21];
    const float* ob1  = (const float*)d_in[22];
    const float* oW2  = (const float*)d_in[23];
    const float* ob2  = (const float*)d_in[24];
    const float* oW3  = (const float*)d_in[25];
    const float* ob3  = (const float*)d_in[26];
    float* out = (float*)d_out;

    const int N = in_sizes[0] / F;
    const int E = in_sizes[2];
    const int G = out_size;         // OUT == 1
    const int npg = N / G;
    const int H1 = 85, H2 = 64;     // int(128/1.5), 128//2
    const int Etot = 2 * E + N;

    // workspace carve-up (256B aligned)
    char* w = (char*)d_ws;
    auto carve = [&](size_t bytes) {
        void* p = (void*)w;
        w += (bytes + 255) & ~(size_t)255;
        return p;
    };
    int*   deg     = (int*)  carve((size_t)N * 4);
    int*   row_ptr = (int*)  carve((size_t)(N + 1) * 4);
    int*   cursor  = (int*)  carve((size_t)N * 4);
    int*   col     = (int*)  carve((size_t)Etot * 4);
    float* glogit  = (float*)carve((size_t)N * 4);
    float* hA      = (float*)carve((size_t)N * F * 4);
    float* hB      = (float*)carve((size_t)N * F * 4);
    float* mbuf    = (float*)carve((size_t)N * F * 4);
    float* pooled  = (float*)carve((size_t)G * F * 4);
    (void)ws_size; (void)n_in;

    // --- CSR build ---
    hipMemsetAsync(deg, 0, (size_t)N * 4, stream);
    int eb = (Etot + 255) / 256;
    count_edges<<<eb, 256, 0, stream>>>(ei, ea, t, deg, E, N);
    scan_deg<<<1, 256, 0, stream>>>(deg, row_ptr, N);
    copy_int<<<(N + 255) / 256, 256, 0, stream>>>(row_ptr, cursor, N);
    scatter_edges<<<eb, 256, 0, stream>>>(ei, ea, t, cursor, col, E, N);

    // --- h = x ---
    hipMemcpyAsync(hA, x, (size_t)N * F * 4, hipMemcpyDeviceToDevice, stream);

    float* hc = hA;
    float* hn = hB;
    for (int it = 0; it < PROP_ITER; it++) {
        gate_mlp<<<(N + 15) / 16, 256, 0, stream>>>(hc, gW1, gb1, gW2, gb2, gW3, gb3, glogit, N);
        aggregate<<<N, 64, 0, stream>>>(hc, glogit, row_ptr, col, mbuf, N);
        gru_kernel<<<(N + 31) / 32, 256, 0, stream>>>(mbuf, hc, Wih, Whh, bih, bhh, hn, N);
        float* tmp = hc; hc = hn; hn = tmp;
    }

    // --- final attention (ai1 reuses mbuf, node_out reuses the free h buffer) ---
    attn_l1<<<(N + 7) / 8, 256, 0, stream>>>(hc, x, aiW1, aib1, mbuf, N);
    attn_l2<<<(N + 7) / 8, 256, 0, stream>>>(mbuf, x, aiW2, aib2, ajW, ajb, hn, N);

    hipMemsetAsync(pooled, 0, (size_t)G * F * 4, stream);
    dim3 pg(G, 8);
    pool_kernel<<<pg, 128, 0, stream>>>(hn, pooled, npg, N);
    out_mlp<<<G, 128, 0, stream>>>(pooled, oW1, ob1, oW2, ob2, oW3, ob3, out, H1, H2);
}

// Round 3
// 1333.945 us; speedup vs baseline: 46.5608x; 1.6055x over previous
//
#include <hip/hip_runtime.h>
#include <hip/hip_bf16.h>

#define F 128
#define PROP_ITER 4

typedef unsigned short u16;
typedef __attribute__((ext_vector_type(8))) short bf16x8;
typedef __attribute__((ext_vector_type(4))) float f32x4;

__device__ __forceinline__ float softsign(float v) { return v / (1.0f + fabsf(v)); }
__device__ __forceinline__ float sigmoidf(float v) { return 1.0f / (1.0f + expf(-v)); }
__device__ __forceinline__ u16 f2bf(float f) {            // RTNE f32 -> bf16
    union { float f; unsigned u; } v; v.f = f;
    unsigned r = v.u + 0x7FFF + ((v.u >> 16) & 1);
    return (u16)(r >> 16);
}

// ----------------------------------------------------------------------------
// CSR build: drop masked edges (feat > t); every node keeps its self-loop.
// ----------------------------------------------------------------------------
__global__ __launch_bounds__(256) void count_edges(const int* __restrict__ ei,
                                                   const float* __restrict__ ea,
                                                   const float* __restrict__ t,
                                                   int* __restrict__ deg, int E, int N) {
    int i = blockIdx.x * 256 + threadIdx.x;
    int tot = 2 * E + N;
    if (i >= tot) return;
    int dst; float f;
    if (i < E)            { dst = ei[E + i];   f = ea[i]; }
    else if (i < 2 * E)   { dst = ei[i - E];   f = ea[i - E]; }
    else                  { dst = i - 2 * E;   f = 1.0f; }
    if (f <= t[0]) atomicAdd(&deg[dst], 1);
}

__global__ __launch_bounds__(256) void scan_deg(const int* __restrict__ deg,
                                                int* __restrict__ row_ptr, int N) {
    __shared__ int ssum[256];
    int tid = threadIdx.x;
    int chunk = (N + 255) >> 8;
    int start = tid * chunk;
    int end = start + chunk; if (end > N) end = N; if (start > N) start = N;
    int s = 0;
    for (int i = start; i < end; i++) s += deg[i];
    ssum[tid] = s;
    __syncthreads();
    for (int off = 1; off < 256; off <<= 1) {
        int u = (tid >= off) ? ssum[tid - off] : 0;
        __syncthreads();
        ssum[tid] += u;
        __syncthreads();
    }
    int run = ssum[tid] - s;   // exclusive prefix
    for (int i = start; i < end; i++) { row_ptr[i] = run; run += deg[i]; }
    if (tid == 0) row_ptr[N] = ssum[255];
}

__global__ __launch_bounds__(256) void copy_int(const int* __restrict__ a,
                                                int* __restrict__ b, int n) {
    int i = blockIdx.x * 256 + threadIdx.x;
    if (i < n) b[i] = a[i];
}

__global__ __launch_bounds__(256) void scatter_edges(const int* __restrict__ ei,
                                                     const float* __restrict__ ea,
                                                     const float* __restrict__ t,
                                                     int* __restrict__ cursor,
                                                     int* __restrict__ col, int E, int N) {
    int i = blockIdx.x * 256 + threadIdx.x;
    int tot = 2 * E + N;
    if (i >= tot) return;
    int src, dst; float f;
    if (i < E)            { src = ei[i];      dst = ei[E + i]; f = ea[i]; }
    else if (i < 2 * E)   { src = ei[i];      dst = ei[i - E]; f = ea[i - E]; }
    else                  { src = i - 2 * E;  dst = src;       f = 1.0f; }
    if (f <= t[0]) {
        int p = atomicAdd(&cursor[dst], 1);
        col[p] = src;
    }
}

// ----------------------------------------------------------------------------
// One-time conversions: weights -> bf16, x -> (h f32, h bf16).
// ----------------------------------------------------------------------------
__global__ __launch_bounds__(256) void conv_w(const float* __restrict__ Wih,
                                              const float* __restrict__ Whh,
                                              u16* __restrict__ Wih16,
                                              u16* __restrict__ Whh16, int n) {
    int i = blockIdx.x * 256 + threadIdx.x;
    if (i < n) { Wih16[i] = f2bf(Wih[i]); Whh16[i] = f2bf(Whh[i]); }
}

__global__ __launch_bounds__(256) void conv_x(const float* __restrict__ x,
                                              float* __restrict__ hf,
                                              u16* __restrict__ h16, int n4) {
    int i = blockIdx.x * 256 + threadIdx.x;
    if (i >= n4) return;
    float4 v = reinterpret_cast<const float4*>(x)[i];
    reinterpret_cast<float4*>(hf)[i] = v;
    ushort4 u; u.x = f2bf(v.x); u.y = f2bf(v.y); u.z = f2bf(v.z); u.w = f2bf(v.w);
    reinterpret_cast<ushort4*>(h16)[i] = u;
}

// ----------------------------------------------------------------------------
// Gate MLP: glogit[n] = (ss(ss(h W1+b1) W2+b2) W3+b3).  16 nodes / 256-thr block.
// ----------------------------------------------------------------------------
__global__ __launch_bounds__(256) void gate_mlp(const float* __restrict__ h,
                                                const float* __restrict__ W1, const float* __restrict__ b1,
                                                const float* __restrict__ W2, const float* __restrict__ b2,
                                                const float* __restrict__ W3, const float* __restrict__ b3,
                                                float* __restrict__ glogit, int N) {
    __shared__ float sh[16][130];
    __shared__ float s1[16][66];
    __shared__ float s2[16][34];
    int tid = threadIdx.x;
    int nb = blockIdx.x * 16;
    for (int i = tid; i < 16 * 128; i += 256) {
        int n = i >> 7, k = i & 127;
        int node = nb + n;
        sh[n][k] = (node < N) ? h[node * F + k] : 0.0f;
    }
    __syncthreads();
    {   // layer1: 128 -> 64, 4 cols/thread
        int n = tid >> 4, j4 = tid & 15;
        float a0 = b1[j4 * 4 + 0], a1 = b1[j4 * 4 + 1], a2 = b1[j4 * 4 + 2], a3 = b1[j4 * 4 + 3];
        for (int k = 0; k < 128; k++) {
            float hv = sh[n][k];
            float4 w = *reinterpret_cast<const float4*>(&W1[k * 64 + j4 * 4]);
            a0 += hv * w.x; a1 += hv * w.y; a2 += hv * w.z; a3 += hv * w.w;
        }
        s1[n][j4 * 4 + 0] = softsign(a0);
        s1[n][j4 * 4 + 1] = softsign(a1);
        s1[n][j4 * 4 + 2] = softsign(a2);
        s1[n][j4 * 4 + 3] = softsign(a3);
    }
    __syncthreads();
    {   // layer2: 64 -> 32, 2 cols/thread
        int n = tid >> 4, jj = tid & 15;
        float a0 = b2[jj * 2 + 0], a1 = b2[jj * 2 + 1];
        for (int k = 0; k < 64; k++) {
            float v = s1[n][k];
            float2 w = *reinterpret_cast<const float2*>(&W2[k * 32 + jj * 2]);
            a0 += v * w.x; a1 += v * w.y;
        }
        s2[n][jj * 2 + 0] = softsign(a0);
        s2[n][jj * 2 + 1] = softsign(a1);
    }
    __syncthreads();
    {   // layer3: 32 -> 1, reduce over 16 lanes
        int n = tid >> 4, jj = tid & 15;
        float p = s2[n][jj] * W3[jj] + s2[n][jj + 16] * W3[jj + 16];
        p += __shfl_xor(p, 1);
        p += __shfl_xor(p, 2);
        p += __shfl_xor(p, 4);
        p += __shfl_xor(p, 8);
        if (jj == 0) {
            int node = nb + n;
            if (node < N) glogit[node] = p + b3[0];
        }
    }
}

// ----------------------------------------------------------------------------
// Softmax aggregation over incoming edges (CSR). 1 wave per dst node.
// Writes bf16 m (only consumer is the MFMA GRU).
// ----------------------------------------------------------------------------
__global__ __launch_bounds__(64) void aggregate(const float* __restrict__ h,
                                                const float* __restrict__ glogit,
                                                const int* __restrict__ row_ptr,
                                                const int* __restrict__ col,
                                                u16* __restrict__ m16, int N) {
    int dst = blockIdx.x;
    if (dst >= N) return;
    int lane = threadIdx.x;
    int e0 = row_ptr[dst], e1 = row_ptr[dst + 1];
    float mx = -1e30f;
    for (int e = e0 + lane; e < e1; e += 64) mx = fmaxf(mx, glogit[col[e]]);
    #pragma unroll
    for (int o = 32; o; o >>= 1) mx = fmaxf(mx, __shfl_xor(mx, o));
    float acc0 = 0.0f, acc1 = 0.0f, denom = 0.0f;
    for (int e = e0; e < e1; e++) {
        int s = col[e];
        float w = expf(glogit[s] - mx);
        denom += w;
        acc0 += w * h[s * F + lane];
        acc1 += w * h[s * F + 64 + lane];
    }
    float inv = 1.0f / denom;   // self-loop guarantees denom > 0
    m16[dst * F + lane]      = f2bf(acc0 * inv);
    m16[dst * F + 64 + lane] = f2bf(acc1 * inv);
}

// ----------------------------------------------------------------------------
// GRU via MFMA (bf16 in, f32 accumulate). Block = 32 nodes x 128 feats,
// 4 waves; wave handles 4 patches of (16 nodes x 16 feats), 6 acc quads each
// (gi_r,gi_z,gi_g,gh_r,gh_z,gh_g), K=128 in 4 MFMA steps. No LDS: A-frags
// (own node rows) and B-frags (weight rows, block-shared -> L2) are direct
// 16B global bf16x8 loads matching the documented fragment layout:
//   A: row = lane&15, k = 8*(lane>>4)+j ; D: col = lane&15, row = 4*(lane>>4)+q.
// f32 h is read/updated in place (each element touched by exactly one lane).
// ----------------------------------------------------------------------------
__global__ __launch_bounds__(256) void gru_mfma(const u16* __restrict__ m16,
                                                const u16* __restrict__ h16,
                                                const u16* __restrict__ Wih16,
                                                const u16* __restrict__ Whh16,
                                                const float* __restrict__ bih,
                                                const float* __restrict__ bhh,
                                                float* __restrict__ hf,
                                                u16* __restrict__ h16o, int N) {
    int tid = threadIdx.x;
    int wave = tid >> 6, lane = tid & 63;
    int r = lane & 15, g = lane >> 4;
    int node0 = blockIdx.x * 32;

    #pragma unroll 1
    for (int p = 0; p < 4; p++) {
        int nsub = p & 1;
        int fsub = wave * 2 + (p >> 1);
        int n0 = node0 + nsub * 16;
        int f0 = fsub * 16;
        int arow = n0 + r; if (arow >= N) arow = N - 1;   // clamp: D rows >= N not stored
        int frow = f0 + r;
        f32x4 a_ir = {0,0,0,0}, a_iz = {0,0,0,0}, a_ig = {0,0,0,0};
        f32x4 a_hr = {0,0,0,0}, a_hz = {0,0,0,0}, a_hg = {0,0,0,0};
        #pragma unroll
        for (int k0 = 0; k0 < 4; k0++) {
            int ko = k0 * 32 + g * 8;
            bf16x8 am  = *reinterpret_cast<const bf16x8*>(m16 + (size_t)arow * F + ko);
            bf16x8 ah  = *reinterpret_cast<const bf16x8*>(h16 + (size_t)arow * F + ko);
            bf16x8 bir = *reinterpret_cast<const bf16x8*>(Wih16 + (size_t)(frow)       * F + ko);
            bf16x8 biz = *reinterpret_cast<const bf16x8*>(Wih16 + (size_t)(128 + frow) * F + ko);
            bf16x8 big = *reinterpret_cast<const bf16x8*>(Wih16 + (size_t)(256 + frow) * F + ko);
            bf16x8 bhr = *reinterpret_cast<const bf16x8*>(Whh16 + (size_t)(frow)       * F + ko);
            bf16x8 bhz = *reinterpret_cast<const bf16x8*>(Whh16 + (size_t)(128 + frow) * F + ko);
            bf16x8 bhg = *reinterpret_cast<const bf16x8*>(Whh16 + (size_t)(256 + frow) * F + ko);
            a_ir = __builtin_amdgcn_mfma_f32_16x16x32_bf16(am, bir, a_ir, 0, 0, 0);
            a_iz = __builtin_amdgcn_mfma_f32_16x16x32_bf16(am, biz, a_iz, 0, 0, 0);
            a_ig = __builtin_amdgcn_mfma_f32_16x16x32_bf16(am, big, a_ig, 0, 0, 0);
            a_hr = __builtin_amdgcn_mfma_f32_16x16x32_bf16(ah, bhr, a_hr, 0, 0, 0);
            a_hz = __builtin_amdgcn_mfma_f32_16x16x32_bf16(ah, bhz, a_hz, 0, 0, 0);
            a_hg = __builtin_amdgcn_mfma_f32_16x16x32_bf16(ah, bhg, a_hg, 0, 0, 0);
        }
        int fj = f0 + r;
        float bi_r = bih[fj], bi_z = bih[128 + fj], bi_g = bih[256 + fj];
        float bh_r = bhh[fj], bh_z = bhh[128 + fj], bh_g = bhh[256 + fj];
        #pragma unroll
        for (int q = 0; q < 4; q++) {
            int node = n0 + g * 4 + q;
            if (node < N) {
                float ir = a_ir[q] + bi_r, iz = a_iz[q] + bi_z, ig = a_ig[q] + bi_g;
                float hr = a_hr[q] + bh_r, hz = a_hz[q] + bh_z, hg = a_hg[q] + bh_g;
                float rr = sigmoidf(ir + hr);
                float z  = sigmoidf(iz + hz);
                float cand = tanhf(ig + rr * hg);
                float hv = hf[(size_t)node * F + fj];
                float hn = (1.0f - z) * cand + z * hv;
                hf[(size_t)node * F + fj] = hn;
                h16o[(size_t)node * F + fj] = f2bf(hn);
            }
        }
    }
}

// ----------------------------------------------------------------------------
// Final attention: ai1 = ss([h|x] W1 + b1).  8 nodes/block, 4 nodes/thread.
// ----------------------------------------------------------------------------
__global__ __launch_bounds__(256) void attn_l1(const float* __restrict__ h,
                                               const float* __restrict__ x,
                                               const float* __restrict__ W1,
                                               const float* __restrict__ b1,
                                               float* __restrict__ ai1, int N) {
    __shared__ float sf[8][258];
    int tid = threadIdx.x;
    int node0 = blockIdx.x * 8;
    for (int i = tid; i < 8 * 256; i += 256) {
        int n = i >> 8, k = i & 255;
        int nd = node0 + n;
        float v = 0.f;
        if (nd < N) v = (k < 128) ? h[nd * F + k] : x[nd * F + (k - 128)];
        sf[n][k] = v;
    }
    __syncthreads();
    int n2 = tid >> 7, j = tid & 127;
    float a[4];
    #pragma unroll
    for (int i = 0; i < 4; i++) a[i] = b1[j];
    for (int k = 0; k < 256; k++) {
        float w = W1[k * 128 + j];
        a[0] += sf[n2 + 0][k] * w;
        a[1] += sf[n2 + 2][k] * w;
        a[2] += sf[n2 + 4][k] * w;
        a[3] += sf[n2 + 6][k] * w;
    }
    #pragma unroll
    for (int i = 0; i < 4; i++) {
        int nd = node0 + n2 + 2 * i;
        if (nd < N) ai1[nd * F + j] = softsign(a[i]);
    }
}

// ----------------------------------------------------------------------------
// ai2 = ss(ai1 W2 + b2); attn = softmax_row(ai2); aj = ss(x Wj + bj);
// node_out = attn * aj.   8 nodes/block.
// ----------------------------------------------------------------------------
__global__ __launch_bounds__(256) void attn_l2(const float* __restrict__ ai1,
                                               const float* __restrict__ x,
                                               const float* __restrict__ W2,
                                               const float* __restrict__ b2,
                                               const float* __restrict__ Wj,
                                               const float* __restrict__ bj,
                                               float* __restrict__ node_out, int N) {
    __shared__ float sa[8][130];
    __shared__ float sx[8][130];
    __shared__ float sred[8][128];
    int tid = threadIdx.x;
    int node0 = blockIdx.x * 8;
    for (int i = tid; i < 8 * 128; i += 256) {
        int n = i >> 7, k = i & 127;
        int nd = node0 + n;
        sa[n][k] = (nd < N) ? ai1[nd * F + k] : 0.f;
        sx[n][k] = (nd < N) ? x[nd * F + k] : 0.f;
    }
    __syncthreads();
    int n2 = tid >> 7, j = tid & 127;
    float acc[4], accj[4];
    #pragma unroll
    for (int i = 0; i < 4; i++) { acc[i] = b2[j]; accj[i] = bj[j]; }
    for (int k = 0; k < 128; k++) {
        float w2 = W2[k * 128 + j];
        float wj = Wj[k * 128 + j];
        #pragma unroll
        for (int i = 0; i < 4; i++) {
            acc[i]  += sa[n2 + 2 * i][k] * w2;
            accj[i] += sx[n2 + 2 * i][k] * wj;
        }
    }
    float v[4], aj[4];
    #pragma unroll
    for (int i = 0; i < 4; i++) {
        v[i] = softsign(acc[i]);
        aj[i] = softsign(accj[i]);
        sred[n2 + 2 * i][j] = v[i];
    }
    __syncthreads();
    for (int s = 64; s > 0; s >>= 1) {
        if (j < s) {
            #pragma unroll
            for (int i = 0; i < 4; i++) {
                int r = n2 + 2 * i;
                sred[r][j] = fmaxf(sred[r][j], sred[r][j + s]);
            }
        }
        __syncthreads();
    }
    float mx[4];
    #pragma unroll
    for (int i = 0; i < 4; i++) mx[i] = sred[n2 + 2 * i][0];
    __syncthreads();
    float e[4];
    #pragma unroll
    for (int i = 0; i < 4; i++) {
        e[i] = expf(v[i] - mx[i]);
        sred[n2 + 2 * i][j] = e[i];
    }
    __syncthreads();
    for (int s = 64; s > 0; s >>= 1) {
        if (j < s) {
            #pragma unroll
            for (int i = 0; i < 4; i++) {
                int r = n2 + 2 * i;
                sred[r][j] += sred[r][j + s];
            }
        }
        __syncthreads();
    }
    #pragma unroll
    for (int i = 0; i < 4; i++) {
        float sum = sred[n2 + 2 * i][0];
        int nd = node0 + n2 + 2 * i;
        if (nd < N) node_out[nd * F + j] = (e[i] / sum) * aj[i];
    }
}

// ----------------------------------------------------------------------------
// Graph pooling (batch = node / (N/G), contiguous) + out MLP.
// ----------------------------------------------------------------------------
__global__ __launch_bounds__(128) void pool_kernel(const float* __restrict__ node_out,
                                                   float* __restrict__ pooled,
                                                   int npg, int N) {
    int g = blockIdx.x, part = blockIdx.y, j = threadIdx.x;
    int start = g * npg + (part * npg) / 8;
    int end   = g * npg + ((part + 1) * npg) / 8;
    if (end > N) end = N;
    float s = 0.f;
    for (int nd = start; nd < end; nd++) s += node_out[nd * F + j];
    atomicAdd(&pooled[g * F + j], s);
}

__global__ __launch_bounds__(128) void out_mlp(const float* __restrict__ pooled,
                                               const float* __restrict__ W1, const float* __restrict__ b1,
                                               const float* __restrict__ W2, const float* __restrict__ b2,
                                               const float* __restrict__ W3, const float* __restrict__ b3,
                                               float* __restrict__ out, int H1, int H2) {
    __shared__ float sp[128];
    __shared__ float s1[96];
    __shared__ float s2[64];
    int g = blockIdx.x, j = threadIdx.x;
    sp[j] = pooled[g * F + j];
    __syncthreads();
    if (j < H1) {
        float a = b1[j];
        for (int k = 0; k < 128; k++) a += sp[k] * W1[k * H1 + j];
        s1[j] = fmaxf(a, 0.f);
    }
    __syncthreads();
    if (j < H2) {
        float a = b2[j];
        for (int k = 0; k < H1; k++) a += s1[k] * W2[k * H2 + j];
        s2[j] = fmaxf(a, 0.f);
    }
    __syncthreads();
    if (j == 0) {
        float a = b3[0];
        for (int k = 0; k < H2; k++) a += s2[k] * W3[k];
        out[g] = a;
    }
}

// ----------------------------------------------------------------------------
extern "C" void kernel_launch(void* const* d_in, const int* in_sizes, int n_in,
                              void* d_out, int out_size, void* d_ws, size_t ws_size,
                              hipStream_t stream) {
    const float* x    = (const float*)d_in[0];
    const int*   ei   = (const int*)  d_in[1];
    const float* ea   = (const float*)d_in[2];
    const float* t    = (const float*)d_in[4];
    const float* gW1  = (const float*)d_in[5];
    const float* gb1  = (const float*)d_in[6];
    const float* gW2  = (const float*)d_in[7];
    const float* gb2  = (const float*)d_in[8];
    const float* gW3  = (const float*)d_in[9];
    const float* gb3  = (const float*)d_in[10];
    const float* Wih  = (const float*)d_in[11];
    const float* Whh  = (const float*)d_in[12];
    const float* bih  = (const float*)d_in[13];
    const float* bhh  = (const float*)d_in[14];
    const float* aiW1 = (const float*)d_in[15];
    const float* aib1 = (const float*)d_in[16];
    const float* aiW2 = (const float*)d_in[17];
    const float* aib2 = (const float*)d_in[18];
    const float* ajW  = (const float*)d_in[19];
    const float* ajb  = (const float*)d_in[20];
    const float* oW1  = (const float*)d_in[21];
    const float* ob1  = (const float*)d_in[22];
    const float* oW2  = (const float*)d_in[23];
    const float* ob2  = (const float*)d_in[24];
    const float* oW3  = (const float*)d_in[25];
    const float* ob3  = (const float*)d_in[26];
    float* out = (float*)d_out;

    const int N = in_sizes[0] / F;
    const int E = in_sizes[2];
    const int G = out_size;         // OUT == 1
    const int npg = N / G;
    const int H1 = 85, H2 = 64;     // int(128/1.5), 128//2
    const int Etot = 2 * E + N;

    // workspace carve-up (256B aligned)
    char* w = (char*)d_ws;
    auto carve = [&](size_t bytes) {
        void* p = (void*)w;
        w += (bytes + 255) & ~(size_t)255;
        return p;
    };
    int*   deg     = (int*)  carve((size_t)N * 4);
    int*   row_ptr = (int*)  carve((size_t)(N + 1) * 4);
    int*   cursor  = (int*)  carve((size_t)N * 4);
    int*   col     = (int*)  carve((size_t)Etot * 4);
    float* glogit  = (float*)carve((size_t)N * 4);
    float* hA      = (float*)carve((size_t)N * F * 4);   // f32 h, updated in place
    float* mbuf    = (float*)carve((size_t)N * F * 4);   // ai1 scratch
    u16*   m16     = (u16*)  carve((size_t)N * F * 2);   // bf16 m   (+ node_out overlay)
    u16*   h16A    = (u16*)  carve((size_t)N * F * 2);   // bf16 h ping
    u16*   h16B    = (u16*)  carve((size_t)N * F * 2);   // bf16 h pong
    u16*   Wih16   = (u16*)  carve((size_t)384 * F * 2);
    u16*   Whh16   = (u16*)  carve((size_t)384 * F * 2);
    float* pooled  = (float*)carve((size_t)G * F * 4);
    float* node_out = (float*)m16;   // overlay: m16+h16A dead after prop loop (2B*2 = 4B*1)
    (void)ws_size; (void)n_in;

    // --- one-time conversions ---
    conv_w<<<(384 * F + 255) / 256, 256, 0, stream>>>(Wih, Whh, Wih16, Whh16, 384 * F);
    int n4 = N * F / 4;
    conv_x<<<(n4 + 255) / 256, 256, 0, stream>>>(x, hA, h16A, n4);

    // --- CSR build ---
    hipMemsetAsync(deg, 0, (size_t)N * 4, stream);
    int eb = (Etot + 255) / 256;
    count_edges<<<eb, 256, 0, stream>>>(ei, ea, t, deg, E, N);
    scan_deg<<<1, 256, 0, stream>>>(deg, row_ptr, N);
    copy_int<<<(N + 255) / 256, 256, 0, stream>>>(row_ptr, cursor, N);
    scatter_edges<<<eb, 256, 0, stream>>>(ei, ea, t, cursor, col, E, N);

    u16* h16c = h16A;
    u16* h16n = h16B;
    for (int it = 0; it < PROP_ITER; it++) {
        gate_mlp<<<(N + 15) / 16, 256, 0, stream>>>(hA, gW1, gb1, gW2, gb2, gW3, gb3, glogit, N);
        aggregate<<<N, 64, 0, stream>>>(hA, glogit, row_ptr, col, m16, N);
        gru_mfma<<<(N + 31) / 32, 256, 0, stream>>>(m16, h16c, Wih16, Whh16, bih, bhh, hA, h16n, N);
        u16* tmp = h16c; h16c = h16n; h16n = tmp;
    }

    // --- final attention ---
    attn_l1<<<(N + 7) / 8, 256, 0, stream>>>(hA, x, aiW1, aib1, mbuf, N);
    attn_l2<<<(N + 7) / 8, 256, 0, stream>>>(mbuf, x, aiW2, aib2, ajW, ajb, node_out, N);

    hipMemsetAsync(pooled, 0, (size_t)G * F * 4, stream);
    dim3 pg(G, 8);
    pool_kernel<<<pg, 128, 0, stream>>>(node_out, pooled, npg, N);
    out_mlp<<<G, 128, 0, stream>>>(pooled, oW1, ob1, oW2, ob2, oW3, ob3, out, H1, H2);
}

// Round 4
// 908.930 us; speedup vs baseline: 68.3326x; 1.4676x over previous
//
#include <hip/hip_runtime.h>
#include <hip/hip_bf16.h>

#define F 128
#define PROP_ITER 4

typedef unsigned short u16;
typedef unsigned int u32;
typedef __attribute__((ext_vector_type(8))) short bf16x8;
typedef __attribute__((ext_vector_type(4))) float f32x4;

__device__ __forceinline__ float softsign(float v) { return v / (1.0f + fabsf(v)); }
__device__ __forceinline__ float sigmoidf(float v) { return 1.0f / (1.0f + expf(-v)); }
__device__ __forceinline__ u16 f2bf(float f) {            // RTNE f32 -> bf16
    union { float f; unsigned u; } v; v.f = f;
    unsigned r = v.u + 0x7FFF + ((v.u >> 16) & 1);
    return (u16)(r >> 16);
}
__device__ __forceinline__ float bf2f(u32 lo16) {
    union { unsigned u; float f; } v; v.u = lo16 << 16; return v.f;
}

// ----------------------------------------------------------------------------
// CSR build: drop masked edges (feat > t); every node keeps its self-loop.
// ----------------------------------------------------------------------------
__global__ __launch_bounds__(256) void count_edges(const int* __restrict__ ei,
                                                   const float* __restrict__ ea,
                                                   const float* __restrict__ t,
                                                   int* __restrict__ deg, int E, int N) {
    int i = blockIdx.x * 256 + threadIdx.x;
    int tot = 2 * E + N;
    if (i >= tot) return;
    int dst; float f;
    if (i < E)            { dst = ei[E + i];   f = ea[i]; }
    else if (i < 2 * E)   { dst = ei[i - E];   f = ea[i - E]; }
    else                  { dst = i - 2 * E;   f = 1.0f; }
    if (f <= t[0]) atomicAdd(&deg[dst], 1);
}

__global__ __launch_bounds__(256) void scan_deg(const int* __restrict__ deg,
                                                int* __restrict__ row_ptr, int N) {
    __shared__ int ssum[256];
    int tid = threadIdx.x;
    int chunk = (N + 255) >> 8;
    int start = tid * chunk;
    int end = start + chunk; if (end > N) end = N; if (start > N) start = N;
    int s = 0;
    for (int i = start; i < end; i++) s += deg[i];
    ssum[tid] = s;
    __syncthreads();
    for (int off = 1; off < 256; off <<= 1) {
        int u = (tid >= off) ? ssum[tid - off] : 0;
        __syncthreads();
        ssum[tid] += u;
        __syncthreads();
    }
    int run = ssum[tid] - s;   // exclusive prefix
    for (int i = start; i < end; i++) { row_ptr[i] = run; run += deg[i]; }
    if (tid == 0) row_ptr[N] = ssum[255];
}

__global__ __launch_bounds__(256) void copy_int(const int* __restrict__ a,
                                                int* __restrict__ b, int n) {
    int i = blockIdx.x * 256 + threadIdx.x;
    if (i < n) b[i] = a[i];
}

__global__ __launch_bounds__(256) void scatter_edges(const int* __restrict__ ei,
                                                     const float* __restrict__ ea,
                                                     const float* __restrict__ t,
                                                     int* __restrict__ cursor,
                                                     int* __restrict__ col, int E, int N) {
    int i = blockIdx.x * 256 + threadIdx.x;
    int tot = 2 * E + N;
    if (i >= tot) return;
    int src, dst; float f;
    if (i < E)            { src = ei[i];      dst = ei[E + i]; f = ea[i]; }
    else if (i < 2 * E)   { src = ei[i];      dst = ei[i - E]; f = ea[i - E]; }
    else                  { src = i - 2 * E;  dst = src;       f = 1.0f; }
    if (f <= t[0]) {
        int p = atomicAdd(&cursor[dst], 1);
        col[p] = src;
    }
}

// ----------------------------------------------------------------------------
// One-time conversions.
// ----------------------------------------------------------------------------
__global__ __launch_bounds__(256) void conv_w(const float* __restrict__ Wih,
                                              const float* __restrict__ Whh,
                                              u16* __restrict__ Wih16,
                                              u16* __restrict__ Whh16, int n) {
    int i = blockIdx.x * 256 + threadIdx.x;
    if (i < n) { Wih16[i] = f2bf(Wih[i]); Whh16[i] = f2bf(Whh[i]); }
}

__global__ __launch_bounds__(256) void conv_x(const float* __restrict__ x,
                                              float* __restrict__ hf,
                                              u16* __restrict__ h16,
                                              u16* __restrict__ x16, int n4) {
    int i = blockIdx.x * 256 + threadIdx.x;
    if (i >= n4) return;
    float4 v = reinterpret_cast<const float4*>(x)[i];
    reinterpret_cast<float4*>(hf)[i] = v;
    ushort4 u; u.x = f2bf(v.x); u.y = f2bf(v.y); u.z = f2bf(v.z); u.w = f2bf(v.w);
    reinterpret_cast<ushort4*>(h16)[i] = u;
    reinterpret_cast<ushort4*>(x16)[i] = u;
}

// WT[c][r] = bf16(W[r][c]);  W is [R][C] row-major -> WT is [C][R].
__global__ __launch_bounds__(256) void transp_bf16(const float* __restrict__ W,
                                                   u16* __restrict__ WT, int R, int C) {
    int i = blockIdx.x * 256 + threadIdx.x;
    if (i >= R * C) return;
    int c = i / R, r = i - c * R;
    WT[i] = f2bf(W[(size_t)r * C + c]);
}

// ----------------------------------------------------------------------------
// Gate MLP via MFMA. Block = 32 nodes, 4 waves.
// L1 (128->64): wave w owns cols [w*16, w*16+16), patches nsub=0,1 (K=128).
// L2 (64->32):  wave w -> (nsub=w>>1, fsub=w&1) (K=64).
// L3 (32->1):   8 threads/row shuffle-dot.
// ----------------------------------------------------------------------------
__global__ __launch_bounds__(256) void gate_mfma(const u16* __restrict__ h16,
                                                 const u16* __restrict__ gW1T,  // [64][128]
                                                 const float* __restrict__ gb1,
                                                 const u16* __restrict__ gW2T,  // [32][64]
                                                 const float* __restrict__ gb2,
                                                 const float* __restrict__ gW3, // [32]
                                                 const float* __restrict__ gb3,
                                                 float* __restrict__ glogit, int N) {
    __shared__ u16 s1[32][72];     // stride 144B: 16B-aligned, 2-way bank alias (free)
    __shared__ float s2[32][36];
    int tid = threadIdx.x;
    int wave = tid >> 6, lane = tid & 63, r = lane & 15, g = lane >> 4;
    int node0 = blockIdx.x * 32;

    #pragma unroll 1
    for (int p = 0; p < 2; p++) {
        int f0 = wave * 16, j = f0 + r;
        int arow = node0 + p * 16 + r; if (arow >= N) arow = N - 1;
        f32x4 acc = {0, 0, 0, 0};
        #pragma unroll
        for (int k0 = 0; k0 < 4; k0++) {
            int ko = k0 * 32 + g * 8;
            bf16x8 a = *reinterpret_cast<const bf16x8*>(h16 + (size_t)arow * F + ko);
            bf16x8 b = *reinterpret_cast<const bf16x8*>(gW1T + (size_t)j * 128 + ko);
            acc = __builtin_amdgcn_mfma_f32_16x16x32_bf16(a, b, acc, 0, 0, 0);
        }
        float bb = gb1[j];
        #pragma unroll
        for (int q = 0; q < 4; q++)
            s1[p * 16 + 4 * g + q][j] = f2bf(softsign(acc[q] + bb));
    }
    __syncthreads();
    {
        int nsub = wave >> 1, f0 = (wave & 1) * 16, j = f0 + r;
        f32x4 acc = {0, 0, 0, 0};
        #pragma unroll
        for (int k0 = 0; k0 < 2; k0++) {
            int ko = k0 * 32 + g * 8;
            bf16x8 a = *reinterpret_cast<const bf16x8*>(&s1[nsub * 16 + r][ko]);
            bf16x8 b = *reinterpret_cast<const bf16x8*>(gW2T + (size_t)j * 64 + ko);
            acc = __builtin_amdgcn_mfma_f32_16x16x32_bf16(a, b, acc, 0, 0, 0);
        }
        float bb = gb2[j];
        #pragma unroll
        for (int q = 0; q < 4; q++)
            s2[nsub * 16 + 4 * g + q][j] = softsign(acc[q] + bb);
    }
    __syncthreads();
    {
        int row = tid >> 3, c0 = (tid & 7) * 4;
        float s = 0.f;
        #pragma unroll
        for (int i = 0; i < 4; i++) s += s2[row][c0 + i] * gW3[c0 + i];
        s += __shfl_xor(s, 1);
        s += __shfl_xor(s, 2);
        s += __shfl_xor(s, 4);
        if ((tid & 7) == 0) {
            int node = node0 + row;
            if (node < N) glogit[node] = s + gb3[0];
        }
    }
}

// ----------------------------------------------------------------------------
// Softmax aggregation over incoming edges (CSR). 1 wave per dst node.
// Gathers bf16 h (2 cols/lane, 4B contiguous), writes bf16 m.
// ----------------------------------------------------------------------------
__global__ __launch_bounds__(64) void aggregate(const u16* __restrict__ h16,
                                                const float* __restrict__ glogit,
                                                const int* __restrict__ row_ptr,
                                                const int* __restrict__ col,
                                                u16* __restrict__ m16, int N) {
    int dst = blockIdx.x;
    if (dst >= N) return;
    int lane = threadIdx.x;
    int e0 = row_ptr[dst], e1 = row_ptr[dst + 1];
    float mx = -1e30f;
    for (int e = e0 + lane; e < e1; e += 64) mx = fmaxf(mx, glogit[col[e]]);
    #pragma unroll
    for (int o = 32; o; o >>= 1) mx = fmaxf(mx, __shfl_xor(mx, o));
    float acc0 = 0.0f, acc1 = 0.0f, denom = 0.0f;
    for (int e = e0; e < e1; e++) {
        int s = col[e];
        float w = expf(glogit[s] - mx);
        denom += w;
        u32 u = *reinterpret_cast<const u32*>(h16 + (size_t)s * F + 2 * lane);
        acc0 += w * bf2f(u & 0xffff);
        acc1 += w * bf2f(u >> 16);
    }
    float inv = 1.0f / denom;   // self-loop guarantees denom > 0
    u32 o = (u32)f2bf(acc0 * inv) | ((u32)f2bf(acc1 * inv) << 16);
    *reinterpret_cast<u32*>(m16 + (size_t)dst * F + 2 * lane) = o;
}

// ----------------------------------------------------------------------------
// GRU via MFMA (validated round 3). Block = 32 nodes, 4 waves.
// ----------------------------------------------------------------------------
__global__ __launch_bounds__(256) void gru_mfma(const u16* __restrict__ m16,
                                                const u16* __restrict__ h16,
                                                const u16* __restrict__ Wih16,
                                                const u16* __restrict__ Whh16,
                                                const float* __restrict__ bih,
                                                const float* __restrict__ bhh,
                                                float* __restrict__ hf,
                                                u16* __restrict__ h16o, int N) {
    int tid = threadIdx.x;
    int wave = tid >> 6, lane = tid & 63;
    int r = lane & 15, g = lane >> 4;
    int node0 = blockIdx.x * 32;

    #pragma unroll 1
    for (int p = 0; p < 4; p++) {
        int nsub = p & 1;
        int fsub = wave * 2 + (p >> 1);
        int n0 = node0 + nsub * 16;
        int f0 = fsub * 16;
        int arow = n0 + r; if (arow >= N) arow = N - 1;
        int frow = f0 + r;
        f32x4 a_ir = {0,0,0,0}, a_iz = {0,0,0,0}, a_ig = {0,0,0,0};
        f32x4 a_hr = {0,0,0,0}, a_hz = {0,0,0,0}, a_hg = {0,0,0,0};
        #pragma unroll
        for (int k0 = 0; k0 < 4; k0++) {
            int ko = k0 * 32 + g * 8;
            bf16x8 am  = *reinterpret_cast<const bf16x8*>(m16 + (size_t)arow * F + ko);
            bf16x8 ah  = *reinterpret_cast<const bf16x8*>(h16 + (size_t)arow * F + ko);
            bf16x8 bir = *reinterpret_cast<const bf16x8*>(Wih16 + (size_t)(frow)       * F + ko);
            bf16x8 biz = *reinterpret_cast<const bf16x8*>(Wih16 + (size_t)(128 + frow) * F + ko);
            bf16x8 big = *reinterpret_cast<const bf16x8*>(Wih16 + (size_t)(256 + frow) * F + ko);
            bf16x8 bhr = *reinterpret_cast<const bf16x8*>(Whh16 + (size_t)(frow)       * F + ko);
            bf16x8 bhz = *reinterpret_cast<const bf16x8*>(Whh16 + (size_t)(128 + frow) * F + ko);
            bf16x8 bhg = *reinterpret_cast<const bf16x8*>(Whh16 + (size_t)(256 + frow) * F + ko);
            a_ir = __builtin_amdgcn_mfma_f32_16x16x32_bf16(am, bir, a_ir, 0, 0, 0);
            a_iz = __builtin_amdgcn_mfma_f32_16x16x32_bf16(am, biz, a_iz, 0, 0, 0);
            a_ig = __builtin_amdgcn_mfma_f32_16x16x32_bf16(am, big, a_ig, 0, 0, 0);
            a_hr = __builtin_amdgcn_mfma_f32_16x16x32_bf16(ah, bhr, a_hr, 0, 0, 0);
            a_hz = __builtin_amdgcn_mfma_f32_16x16x32_bf16(ah, bhz, a_hz, 0, 0, 0);
            a_hg = __builtin_amdgcn_mfma_f32_16x16x32_bf16(ah, bhg, a_hg, 0, 0, 0);
        }
        int fj = f0 + r;
        float bi_r = bih[fj], bi_z = bih[128 + fj], bi_g = bih[256 + fj];
        float bh_r = bhh[fj], bh_z = bhh[128 + fj], bh_g = bhh[256 + fj];
        #pragma unroll
        for (int q = 0; q < 4; q++) {
            int node = n0 + g * 4 + q;
            if (node < N) {
                float ir = a_ir[q] + bi_r, iz = a_iz[q] + bi_z, ig = a_ig[q] + bi_g;
                float hr = a_hr[q] + bh_r, hz = a_hz[q] + bh_z, hg = a_hg[q] + bh_g;
                float rr = sigmoidf(ir + hr);
                float z  = sigmoidf(iz + hz);
                float cand = tanhf(ig + rr * hg);
                float hv = hf[(size_t)node * F + fj];
                float hn = (1.0f - z) * cand + z * hv;
                hf[(size_t)node * F + fj] = hn;
                h16o[(size_t)node * F + fj] = f2bf(hn);
            }
        }
    }
}

// ----------------------------------------------------------------------------
// Fused final attention + pooling. Block = 32 nodes, 4 waves.
//  phase1: ai1 = ss([h|x] W1 + b1)           (K=256, MFMA) -> LDS bf16
//  phase2: v  = ss(ai1 W2 + b2)              (K=128, MFMA) -> LDS f32
//  reduce: row max + expsum
//  phase3: aj = ss(x Wj + bj) (MFMA); out = softmax(v) * aj; pool into LDS,
//          then 2 global atomics per column.
// ----------------------------------------------------------------------------
__global__ __launch_bounds__(256) void attn_fused(const u16* __restrict__ h16,
                                                  const u16* __restrict__ x16,
                                                  const u16* __restrict__ W1T,  // [128][256]
                                                  const float* __restrict__ b1,
                                                  const u16* __restrict__ W2T,  // [128][128]
                                                  const float* __restrict__ b2,
                                                  const u16* __restrict__ WjT,  // [128][128]
                                                  const float* __restrict__ bj,
                                                  float* __restrict__ pooled,   // [G][128]
                                                  int N, int npg, int G) {
    __shared__ u16 s_ai[32][136];   // stride 272B: 16B-aligned, 2-way alias (free)
    __shared__ float s_v[32][132];
    __shared__ float s_mx[32], s_sum[32];
    __shared__ float s_pool[2][128];
    int tid = threadIdx.x;
    int wave = tid >> 6, lane = tid & 63, r = lane & 15, g = lane >> 4;
    int node0 = blockIdx.x * 32;

    s_pool[tid >> 7][tid & 127] = 0.f;

    // phase1
    #pragma unroll 1
    for (int p = 0; p < 4; p++) {
        int nsub = p & 1, fsub = wave * 2 + (p >> 1);
        int n0 = node0 + nsub * 16, f0 = fsub * 16;
        int arow = n0 + r; if (arow >= N) arow = N - 1;
        int j = f0 + r;
        f32x4 acc = {0, 0, 0, 0};
        #pragma unroll
        for (int k0 = 0; k0 < 8; k0++) {
            const u16* Asrc = (k0 < 4) ? h16 : x16;
            int ko = (k0 & 3) * 32 + g * 8;
            bf16x8 a = *reinterpret_cast<const bf16x8*>(Asrc + (size_t)arow * F + ko);
            bf16x8 b = *reinterpret_cast<const bf16x8*>(W1T + (size_t)j * 256 + k0 * 32 + g * 8);
            acc = __builtin_amdgcn_mfma_f32_16x16x32_bf16(a, b, acc, 0, 0, 0);
        }
        float bb = b1[j];
        #pragma unroll
        for (int q = 0; q < 4; q++)
            s_ai[nsub * 16 + 4 * g + q][j] = f2bf(softsign(acc[q] + bb));
    }
    __syncthreads();

    // phase2
    #pragma unroll 1
    for (int p = 0; p < 4; p++) {
        int nsub = p & 1, fsub = wave * 2 + (p >> 1);
        int f0 = fsub * 16, j = f0 + r;
        f32x4 acc = {0, 0, 0, 0};
        #pragma unroll
        for (int k0 = 0; k0 < 4; k0++) {
            int ko = k0 * 32 + g * 8;
            bf16x8 a = *reinterpret_cast<const bf16x8*>(&s_ai[nsub * 16 + r][ko]);
            bf16x8 b = *reinterpret_cast<const bf16x8*>(W2T + (size_t)j * 128 + ko);
            acc = __builtin_amdgcn_mfma_f32_16x16x32_bf16(a, b, acc, 0, 0, 0);
        }
        float bb = b2[j];
        #pragma unroll
        for (int q = 0; q < 4; q++)
            s_v[nsub * 16 + 4 * g + q][j] = softsign(acc[q] + bb);
    }
    __syncthreads();

    // row softmax stats: 8 threads/row, 16 cols each
    {
        int row = tid >> 3, c0 = (tid & 7) * 16;
        float mx = -1e30f;
        #pragma unroll
        for (int i = 0; i < 16; i++) mx = fmaxf(mx, s_v[row][c0 + i]);
        mx = fmaxf(mx, __shfl_xor(mx, 1));
        mx = fmaxf(mx, __shfl_xor(mx, 2));
        mx = fmaxf(mx, __shfl_xor(mx, 4));
        float sum = 0.f;
        #pragma unroll
        for (int i = 0; i < 16; i++) sum += expf(s_v[row][c0 + i] - mx);
        sum += __shfl_xor(sum, 1);
        sum += __shfl_xor(sum, 2);
        sum += __shfl_xor(sum, 4);
        if ((tid & 7) == 0) { s_mx[row] = mx; s_sum[row] = sum; }
    }
    __syncthreads();

    // phase3
    int graph0 = node0 / npg;
    #pragma unroll 1
    for (int p = 0; p < 4; p++) {
        int nsub = p & 1, fsub = wave * 2 + (p >> 1);
        int n0 = node0 + nsub * 16, f0 = fsub * 16;
        int arow = n0 + r; if (arow >= N) arow = N - 1;
        int j = f0 + r;
        f32x4 acc = {0, 0, 0, 0};
        #pragma unroll
        for (int k0 = 0; k0 < 4; k0++) {
            int ko = k0 * 32 + g * 8;
            bf16x8 a = *reinterpret_cast<const bf16x8*>(x16 + (size_t)arow * F + ko);
            bf16x8 b = *reinterpret_cast<const bf16x8*>(WjT + (size_t)j * 128 + ko);
            acc = __builtin_amdgcn_mfma_f32_16x16x32_bf16(a, b, acc, 0, 0, 0);
        }
        float bb = bj[j];
        float p0 = 0.f, p1 = 0.f;
        #pragma unroll
        for (int q = 0; q < 4; q++) {
            int brow = nsub * 16 + 4 * g + q;
            int node = node0 + brow;
            if (node < N) {
                float aj = softsign(acc[q] + bb);
                float attn = expf(s_v[brow][j] - s_mx[brow]) / s_sum[brow];
                float val = attn * aj;
                if (node / npg == graph0) p0 += val; else p1 += val;
            }
        }
        if (p0 != 0.f) atomicAdd(&s_pool[0][j], p0);
        if (p1 != 0.f) atomicAdd(&s_pool[1][j], p1);
    }
    __syncthreads();

    {
        int b_ = tid >> 7, colj = tid & 127;
        float v = s_pool[b_][colj];
        int gg = graph0 + b_;
        if (v != 0.f && gg < G) atomicAdd(&pooled[(size_t)gg * F + colj], v);
    }
}

// ----------------------------------------------------------------------------
// Out MLP (G blocks).
// ----------------------------------------------------------------------------
__global__ __launch_bounds__(128) void out_mlp(const float* __restrict__ pooled,
                                               const float* __restrict__ W1, const float* __restrict__ b1,
                                               const float* __restrict__ W2, const float* __restrict__ b2,
                                               const float* __restrict__ W3, const float* __restrict__ b3,
                                               float* __restrict__ out, int H1, int H2) {
    __shared__ float sp[128];
    __shared__ float s1[96];
    __shared__ float s2[64];
    int g = blockIdx.x, j = threadIdx.x;
    sp[j] = pooled[g * F + j];
    __syncthreads();
    if (j < H1) {
        float a = b1[j];
        for (int k = 0; k < 128; k++) a += sp[k] * W1[k * H1 + j];
        s1[j] = fmaxf(a, 0.f);
    }
    __syncthreads();
    if (j < H2) {
        float a = b2[j];
        for (int k = 0; k < H1; k++) a += s1[k] * W2[k * H2 + j];
        s2[j] = fmaxf(a, 0.f);
    }
    __syncthreads();
    if (j == 0) {
        float a = b3[0];
        for (int k = 0; k < H2; k++) a += s2[k] * W3[k];
        out[g] = a;
    }
}

// ----------------------------------------------------------------------------
extern "C" void kernel_launch(void* const* d_in, const int* in_sizes, int n_in,
                              void* d_out, int out_size, void* d_ws, size_t ws_size,
                              hipStream_t stream) {
    const float* x    = (const float*)d_in[0];
    const int*   ei   = (const int*)  d_in[1];
    const float* ea   = (const float*)d_in[2];
    const float* t    = (const float*)d_in[4];
    const float* gW1  = (const float*)d_in[5];
    const float* gb1  = (const float*)d_in[6];
    const float* gW2  = (const float*)d_in[7];
    const float* gb2  = (const float*)d_in[8];
    const float* gW3  = (const float*)d_in[9];
    const float* gb3  = (const float*)d_in[10];
    const float* Wih  = (const float*)d_in[11];
    const float* Whh  = (const float*)d_in[12];
    const float* bih  = (const float*)d_in[13];
    const float* bhh  = (const float*)d_in[14];
    const float* aiW1 = (const float*)d_in[15];
    const float* aib1 = (const float*)d_in[16];
    const float* aiW2 = (const float*)d_in[17];
    const float* aib2 = (const float*)d_in[18];
    const float* ajW  = (const float*)d_in[19];
    const float* ajb  = (const float*)d_in[20];
    const float* oW1  = (const float*)d_in[21];
    const float* ob1  = (const float*)d_in[22];
    const float* oW2  = (const float*)d_in[23];
    const float* ob2  = (const float*)d_in[24];
    const float* oW3  = (const float*)d_in[25];
    const float* ob3  = (const float*)d_in[26];
    float* out = (float*)d_out;

    const int N = in_sizes[0] / F;
    const int E = in_sizes[2];
    const int G = out_size;         // OUT == 1
    const int npg = N / G;
    const int H1 = 85, H2 = 64;     // int(128/1.5), 128//2
    const int Etot = 2 * E + N;

    char* w = (char*)d_ws;
    auto carve = [&](size_t bytes) {
        void* p = (void*)w;
        w += (bytes + 255) & ~(size_t)255;
        return p;
    };
    int*   deg     = (int*)  carve((size_t)N * 4);
    int*   row_ptr = (int*)  carve((size_t)(N + 1) * 4);
    int*   cursor  = (int*)  carve((size_t)N * 4);
    int*   col     = (int*)  carve((size_t)Etot * 4);
    float* glogit  = (float*)carve((size_t)N * 4);
    float* hA      = (float*)carve((size_t)N * F * 4);   // f32 h master (GRU blend)
    u16*   m16     = (u16*)  carve((size_t)N * F * 2);
    u16*   h16A    = (u16*)  carve((size_t)N * F * 2);
    u16*   h16B    = (u16*)  carve((size_t)N * F * 2);
    u16*   x16     = (u16*)  carve((size_t)N * F * 2);
    u16*   Wih16   = (u16*)  carve((size_t)384 * F * 2);
    u16*   Whh16   = (u16*)  carve((size_t)384 * F * 2);
    u16*   W1T     = (u16*)  carve((size_t)128 * 256 * 2);
    u16*   W2T     = (u16*)  carve((size_t)128 * 128 * 2);
    u16*   WjT     = (u16*)  carve((size_t)128 * 128 * 2);
    u16*   gW1T    = (u16*)  carve((size_t)64 * 128 * 2);
    u16*   gW2T    = (u16*)  carve((size_t)32 * 64 * 2);
    float* pooled  = (float*)carve((size_t)G * F * 4);
    (void)ws_size; (void)n_in;

    // --- one-time conversions ---
    conv_w<<<(384 * F + 255) / 256, 256, 0, stream>>>(Wih, Whh, Wih16, Whh16, 384 * F);
    int n4 = N * F / 4;
    conv_x<<<(n4 + 255) / 256, 256, 0, stream>>>(x, hA, h16A, x16, n4);
    transp_bf16<<<(256 * 128 + 255) / 256, 256, 0, stream>>>(aiW1, W1T, 256, 128);
    transp_bf16<<<(128 * 128 + 255) / 256, 256, 0, stream>>>(aiW2, W2T, 128, 128);
    transp_bf16<<<(128 * 128 + 255) / 256, 256, 0, stream>>>(ajW, WjT, 128, 128);
    transp_bf16<<<(128 * 64 + 255) / 256, 256, 0, stream>>>(gW1, gW1T, 128, 64);
    transp_bf16<<<(64 * 32 + 255) / 256, 256, 0, stream>>>(gW2, gW2T, 64, 32);

    // --- CSR build ---
    hipMemsetAsync(deg, 0, (size_t)N * 4, stream);
    int eb = (Etot + 255) / 256;
    count_edges<<<eb, 256, 0, stream>>>(ei, ea, t, deg, E, N);
    scan_deg<<<1, 256, 0, stream>>>(deg, row_ptr, N);
    copy_int<<<(N + 255) / 256, 256, 0, stream>>>(row_ptr, cursor, N);
    scatter_edges<<<eb, 256, 0, stream>>>(ei, ea, t, cursor, col, E, N);

    u16* h16c = h16A;
    u16* h16n = h16B;
    int nb32 = (N + 31) / 32;
    for (int it = 0; it < PROP_ITER; it++) {
        gate_mfma<<<nb32, 256, 0, stream>>>(h16c, gW1T, gb1, gW2T, gb2, gW3, gb3, glogit, N);
        aggregate<<<N, 64, 0, stream>>>(h16c, glogit, row_ptr, col, m16, N);
        gru_mfma<<<nb32, 256, 0, stream>>>(m16, h16c, Wih16, Whh16, bih, bhh, hA, h16n, N);
        u16* tmp = h16c; h16c = h16n; h16n = tmp;
    }

    // --- fused attention + pooling ---
    hipMemsetAsync(pooled, 0, (size_t)G * F * 4, stream);
    attn_fused<<<nb32, 256, 0, stream>>>(h16c, x16, W1T, aib1, W2T, aib2, WjT, ajb,
                                         pooled, N, npg, G);
    out_mlp<<<G, 128, 0, stream>>>(pooled, oW1, ob1, oW2, ob2, oW3, ob3, out, H1, H2);
}